// Round 1
// baseline (83.927 us; speedup 1.0000x reference)
//
#include <hip/hip_runtime.h>

#define B_  32
#define H_  512
#define W_  512
#define HW_ (H_ * W_)
#define TOTAL_ (B_ * HW_)

__device__ __forceinline__ float weno_minus(float vmm, float vm, float vp) {
    // left-biased u_minus
    float b0 = vmm - vm; b0 *= b0;
    float b1 = vm - vp;  b1 *= b1;
    float t0 = 1e-6f + b0;
    float t1 = 1e-6f + b1;
    float a0 = (1.0f / 3.0f) / (t0 * t0);
    float a1 = (2.0f / 3.0f) / (t1 * t1);
    float w0 = a0 / (a0 + a1);
    return w0 * (0.5f * (-vmm + 3.0f * vm)) + (1.0f - w0) * (0.5f * (vm + vp));
}

__device__ __forceinline__ float weno_plus(float vmm, float vm, float vp) {
    // right-biased u_plus
    float b0 = vp - vm;  b0 *= b0;
    float b1 = vm - vmm; b1 *= b1;
    float t0 = 1e-6f + b0;
    float t1 = 1e-6f + b1;
    float a0 = (1.0f / 3.0f) / (t0 * t0);
    float a1 = (2.0f / 3.0f) / (t1 * t1);
    float w0 = a0 / (a0 + a1);
    return w0 * (0.5f * (-vp + 3.0f * vm)) + (1.0f - w0) * (0.5f * (vm + vmm));
}

__global__ __launch_bounds__(256) void eikonal_main(
        const float* __restrict__ pred, const float* __restrict__ reach,
        double* __restrict__ acc) {
    // target = 1/sqrt(511^2 + 511^2)
    const float target = 1.0f / sqrtf((float)(511 * 511 + 511 * 511));
    const float lo = 0.3f * target;
    const float hi = 5.0f * target;

    float num = 0.0f;
    float den = 0.0f;

    for (int idx = blockIdx.x * blockDim.x + threadIdx.x; idx < TOTAL_;
         idx += gridDim.x * blockDim.x) {
        int x = idx & (W_ - 1);
        int y = (idx >> 9) & (H_ - 1);
        int rowbase = idx - x;           // b*HW + y*W
        int colbase = idx - (y << 9);    // b*HW + x  (still needs +y*W per row)

        const float* row = pred + rowbase;

        // x-direction clamped neighbors
        int xm2 = x - 2 < 0 ? 0 : x - 2;
        int xm1 = x - 1 < 0 ? 0 : x - 1;
        int xp1 = x + 1 > W_ - 1 ? W_ - 1 : x + 1;
        int xp2 = x + 2 > W_ - 1 ? W_ - 1 : x + 2;

        float fxm2 = row[xm2];
        float fxm1 = row[xm1];
        float f0   = row[x];
        float fxp1 = row[xp1];
        float fxp2 = row[xp2];

        float vx_mm = fxm1 - fxm2;
        float vx_m  = f0   - fxm1;
        float vx_c  = fxp1 - f0;
        float vx_p  = fxp2 - fxp1;

        float ux_minus = weno_minus(vx_mm, vx_m, vx_c);
        float ux_plus  = weno_plus(vx_m, vx_c, vx_p);
        float gx = fmaxf(fmaxf(ux_minus, -ux_plus), 0.0f);

        // y-direction clamped neighbors
        int ym2 = y - 2 < 0 ? 0 : y - 2;
        int ym1 = y - 1 < 0 ? 0 : y - 1;
        int yp1 = y + 1 > H_ - 1 ? H_ - 1 : y + 1;
        int yp2 = y + 2 > H_ - 1 ? H_ - 1 : y + 2;

        const float* col = pred + colbase;
        float fym2 = col[ym2 << 9];
        float fym1 = col[ym1 << 9];
        float fyp1 = col[yp1 << 9];
        float fyp2 = col[yp2 << 9];

        float vy_mm = fym1 - fym2;
        float vy_m  = f0   - fym1;
        float vy_c  = fyp1 - f0;
        float vy_p  = fyp2 - fyp1;

        float uy_minus = weno_minus(vy_mm, vy_m, vy_c);
        float uy_plus  = weno_plus(vy_m, vy_c, vy_p);
        float gy = fmaxf(fmaxf(uy_minus, -uy_plus), 0.0f);

        float gmag = sqrtf(gx * gx + gy * gy + 1e-8f);

        float residual = gmag - target;
        float ar = fabsf(residual);
        float per_pixel = (ar < 0.01f) ? (0.5f * residual * residual / 0.01f)
                                       : (ar - 0.005f);

        float r = reach[idx];
        bool m = (r > 0.5f) && (gmag >= lo) && (gmag <= hi);
        if (m) {
            num += per_pixel;
            den += 1.0f;
        }
    }

    // wave reduce (64 lanes) in double
    double dn = (double)num;
    double dd = (double)den;
    #pragma unroll
    for (int off = 32; off > 0; off >>= 1) {
        dn += __shfl_down(dn, off);
        dd += __shfl_down(dd, off);
    }

    __shared__ double sn[4], sd[4];
    int wid = threadIdx.x >> 6;
    int lane = threadIdx.x & 63;
    if (lane == 0) { sn[wid] = dn; sd[wid] = dd; }
    __syncthreads();
    if (threadIdx.x == 0) {
        double tn = sn[0] + sn[1] + sn[2] + sn[3];
        double td = sd[0] + sd[1] + sd[2] + sd[3];
        atomicAdd(&acc[0], tn);
        atomicAdd(&acc[1], td);
    }
}

__global__ void eikonal_finalize(const double* __restrict__ acc,
                                 float* __restrict__ out) {
    double den = acc[1];
    if (den < 1e-8) den = 1e-8;
    out[0] = (float)(acc[0] / den);
}

extern "C" void kernel_launch(void* const* d_in, const int* in_sizes, int n_in,
                              void* d_out, int out_size, void* d_ws, size_t ws_size,
                              hipStream_t stream) {
    const float* pred  = (const float*)d_in[0];
    const float* reach = (const float*)d_in[1];
    float* out = (float*)d_out;
    double* acc = (double*)d_ws;

    hipMemsetAsync(d_ws, 0, 2 * sizeof(double), stream);

    const int block = 256;
    const int grid = 2048;  // grid-stride: 8.4M pixels / 524288 threads = 16 px/thread
    eikonal_main<<<grid, block, 0, stream>>>(pred, reach, acc);
    eikonal_finalize<<<1, 1, 0, stream>>>(acc, out);
}